// Round 5
// baseline (82.811 us; speedup 1.0000x reference)
//
#include <hip/hip_runtime.h>
#include <hip/hip_cooperative_groups.h>
#include <math.h>

namespace cg = cooperative_groups;

#define LC 8
#define FAC 120
#define KS 5
#define KK 25
#define IWID 64
#define NH 60
#define SS 3600
#define PIXB 256
#define NBLK 225        // 57600/256 pixel-blocks, <= 256 CUs (co-resident)

using bf16x8 = __attribute__((ext_vector_type(8))) short;
using f32x4  = __attribute__((ext_vector_type(4))) float;

// ws layout: [0,65536) M_hi [8][128][32] bf16 ; [65536,131072) M_lo ; [131072,+32) msq[8] f32
#define MS_LO_OFF 32768   // in shorts
#define MSQ_BYTE  131072

__device__ __forceinline__ short f2bf(float v) {
  unsigned u = __builtin_bit_cast(unsigned, v);
  unsigned r = u + 0x7FFFu + ((u >> 16) & 1u);
  return (short)(r >> 16);
}
__device__ __forceinline__ float bf2f(short h) {
  unsigned u = ((unsigned)(unsigned short)h) << 16;
  return __builtin_bit_cast(float, u);
}

__global__ __launch_bounds__(256, 1) void fused(const float* __restrict__ x,
                                                const float* __restrict__ kern,
                                                void* __restrict__ wsv,
                                                float* __restrict__ out) {
  __shared__ short pat_hi[PIXB][32];
  __shared__ short pat_lo[PIXB][32];
  __shared__ float xsq_s[PIXB];
  __shared__ float red[4];

  const int tid = threadIdx.x;
  const int bid = blockIdx.x;
  short* MH = (short*)wsv;
  short* ML = MH + MS_LO_OFF;
  float* MSQ = (float*)((char*)wsv + MSQ_BYTE);

  // ---------------- phase 0: build split M tables + msq (blocks 0..3) ----------------
  const int gid = bid * 256 + tid;
  if (gid < 1024) {
    const int l = gid >> 7;
    const int f = gid & 127;
    short* h = MH + gid * 32;
    short* lo = ML + gid * 32;
    if (f < FAC) {
      int avail[KS] = {0, 1, 2, 3, 4};
      int perm[KS];
      int rem = f;
      const int divs[4] = {24, 6, 2, 1};
      for (int i = 0; i < 4; ++i) {
        const int d = rem / divs[i];
        rem -= d * divs[i];
        perm[i] = avail[d];
        for (int j = d; j < 4 - i; ++j) avail[j] = avail[j + 1];
      }
      perm[4] = avail[0];
      const float* Kl = kern + l * KK;
      #pragma unroll
      for (int a = 0; a < KS; ++a)
        #pragma unroll
        for (int d = 0; d < KS; ++d) {
          const float v = Kl[perm[a] * KS + perm[d]];
          const short hs = f2bf(v);
          h[a * KS + d] = hs;
          lo[a * KS + d] = f2bf(v - bf2f(hs));
        }
      #pragma unroll
      for (int q = KK; q < 32; ++q) { h[q] = 0; lo[q] = 0; }
      if (f == 0) {
        float s = 0.f;
        #pragma unroll
        for (int q = 0; q < KK; ++q) s = fmaf(Kl[q], Kl[q], s);
        MSQ[l] = s;
      }
    } else {
      #pragma unroll
      for (int q = 0; q < 32; ++q) { h[q] = 0; lo[q] = 0; }
    }
  }
  if (bid == 4) {
    for (int i = tid; i < LC * KK; i += 256) out[460800 + i] = kern[i];
  }
  cg::this_grid().sync();

  // ---------------- phase 1: MFMA cross term + max reduce + feature ----------------
  const int w = tid >> 6;
  const int lane = tid & 63;
  const int u0 = bid * PIXB;
  {
    const int u = u0 + tid;
    const int plane = u / SS;
    const int s = u - plane * SS;
    const int ih = s / NH;
    const int iw = s - ih * NH;
    const float* xb = x + plane * (IWID * IWID) + ih * IWID + iw;
    float p[KK];
    #pragma unroll
    for (int a = 0; a < KS; ++a)
      #pragma unroll
      for (int d = 0; d < KS; ++d)
        p[a * KS + d] = xb[a * IWID + d];
    float xs = 0.f;
    #pragma unroll
    for (int q = 0; q < KK; ++q) xs = fmaf(p[q], p[q], xs);
    xsq_s[tid] = xs;
    #pragma unroll
    for (int q = 0; q < KK; ++q) {
      const short hs = f2bf(p[q]);
      pat_hi[tid][q] = hs;
      pat_lo[tid][q] = f2bf(p[q] - bf2f(hs));
    }
    #pragma unroll
    for (int q = KK; q < 32; ++q) { pat_hi[tid][q] = 0; pat_lo[tid][q] = 0; }
  }
  __syncthreads();

  // B fragments + xsq: registers, once (reused across all 8 l)
  bf16x8 BH[4], BL[4];
  float xs4[4];
  #pragma unroll
  for (int j = 0; j < 4; ++j) {
    const int prow = (w << 6) + (j << 4) + (lane & 15);
    BH[j] = *(const bf16x8*)&pat_hi[prow][(lane >> 4) * 8];
    BL[j] = *(const bf16x8*)&pat_lo[prow][(lane >> 4) * 8];
    xs4[j] = xsq_s[prow];
  }

  const short* abase = MH + ((lane & 15) * 32) + ((lane >> 4) * 8);

  auto LOADA = [&](bf16x8* Ah, bf16x8* Al, int l) {
    const short* bh = abase + l * 4096;
    #pragma unroll
    for (int t = 0; t < 8; ++t) {
      Ah[t] = *(const bf16x8*)(bh + t * 512);
      Al[t] = *(const bf16x8*)(bh + t * 512 + MS_LO_OFF);
    }
  };

  auto COMPUTE = [&](const bf16x8* Ah, const bf16x8* Al, int l) {
    const float ml = MSQ[l];
    float mx[4];
    #pragma unroll
    for (int j = 0; j < 4; ++j) mx[j] = -INFINITY;
    #pragma unroll
    for (int t = 0; t < 8; ++t) {
      #pragma unroll
      for (int j = 0; j < 4; ++j) {
        f32x4 C = f32x4{0.f, 0.f, 0.f, 0.f};
        C = __builtin_amdgcn_mfma_f32_16x16x32_bf16(Ah[t], BH[j], C, 0, 0, 0);
        C = __builtin_amdgcn_mfma_f32_16x16x32_bf16(Al[t], BH[j], C, 0, 0, 0);
        C = __builtin_amdgcn_mfma_f32_16x16x32_bf16(Ah[t], BL[j], C, 0, 0, 0);
        if (t < 7) {
          #pragma unroll
          for (int r = 0; r < 4; ++r) mx[j] = fmaxf(mx[j], C[r]);
        } else if (lane < 32) {   // f-rows 112+(lane>>4)*4+r valid only for f<120
          #pragma unroll
          for (int r = 0; r < 4; ++r) mx[j] = fmaxf(mx[j], C[r]);
        }
      }
    }
    #pragma unroll
    for (int j = 0; j < 4; ++j) {
      float m = mx[j];
      m = fmaxf(m, __shfl_xor(m, 16));
      m = fmaxf(m, __shfl_xor(m, 32));
      const float fv = ml + xs4[j] - 2.f * m;
      if (lane < 16) {
        const int up = u0 + (w << 6) + (j << 4) + lane;
        const int pl = up / SS;
        const int sx = up - pl * SS;
        out[(((pl >> 1) * 16) + ((pl & 1) * 8) + l) * SS + sx] = fv;
      }
    }
  };

  // explicit ping-pong over l: static buffers, loads issued one l ahead
  bf16x8 Ah0[8], Al0[8], Ah1[8], Al1[8];
  LOADA(Ah0, Al0, 0);
  LOADA(Ah1, Al1, 1);
  COMPUTE(Ah0, Al0, 0);
  LOADA(Ah0, Al0, 2);
  COMPUTE(Ah1, Al1, 1);
  LOADA(Ah1, Al1, 3);
  COMPUTE(Ah0, Al0, 2);
  LOADA(Ah0, Al0, 4);
  COMPUTE(Ah1, Al1, 3);
  LOADA(Ah1, Al1, 5);
  COMPUTE(Ah0, Al0, 4);
  LOADA(Ah0, Al0, 6);
  COMPUTE(Ah1, Al1, 5);
  LOADA(Ah1, Al1, 7);
  COMPUTE(Ah0, Al0, 6);
  COMPUTE(Ah1, Al1, 7);

  cg::this_grid().sync();

  // ---------------- phase 2: softmax over S per (b,c) row (blocks 0..127) ----------------
  if (bid < 128) {
    float* __restrict__ dr = out + bid * SS;
    float v[15];
    float mn = INFINITY;
    #pragma unroll
    for (int i = 0; i < 15; ++i) {
      const int s = tid + i * 256;
      const float f = (s < SS) ? dr[s] : INFINITY;
      v[i] = f;
      mn = fminf(mn, f);
    }
    #pragma unroll
    for (int off = 32; off >= 1; off >>= 1) mn = fminf(mn, __shfl_xor(mn, off));
    if ((tid & 63) == 0) red[tid >> 6] = mn;
    __syncthreads();
    const float tmn = fminf(fminf(red[0], red[1]), fminf(red[2], red[3]));
    __syncthreads();
    float sum = 0.f;
    #pragma unroll
    for (int i = 0; i < 15; ++i) {
      const float e = expf(tmn - v[i]);   // OOB: exp(-inf)=0
      v[i] = e;
      sum += e;
    }
    #pragma unroll
    for (int off = 32; off >= 1; off >>= 1) sum += __shfl_xor(sum, off);
    if ((tid & 63) == 0) red[tid >> 6] = sum;
    __syncthreads();
    const float inv = 1.0f / (red[0] + red[1] + red[2] + red[3]);
    #pragma unroll
    for (int i = 0; i < 15; ++i) {
      const int s = tid + i * 256;
      if (s < SS) dr[s] = v[i] * inv;
    }
  }
}

extern "C" void kernel_launch(void* const* d_in, const int* in_sizes, int n_in,
                              void* d_out, int out_size, void* d_ws, size_t ws_size,
                              hipStream_t stream) {
  const float* x = (const float*)d_in[0];
  const float* kern = (const float*)d_in[1];
  float* out = (float*)d_out;
  void* ws = d_ws;
  void* args[] = {(void*)&x, (void*)&kern, (void*)&ws, (void*)&out};
  hipLaunchCooperativeKernel((const void*)fused, dim3(NBLK), dim3(256), args, 0, stream);
}

// Round 6
// 33.064 us; speedup vs baseline: 2.5046x; 2.5046x over previous
//
#include <hip/hip_runtime.h>
#include <math.h>

#define LC 8
#define FAC 120
#define KS 5
#define KK 25
#define IWID 64
#define NH 60
#define SS 3600
#define PIXB 128         // pixels per block (k2)
#define NBLK2 450        // 57600/128
#define PADW 40          // shorts per pat row (80B -> 20-bank stride, no conflicts)

using bf16x8 = __attribute__((ext_vector_type(8))) short;
using f32x4  = __attribute__((ext_vector_type(4))) float;

// ws layout: [0,65536) M_hi [8][128][32] bf16 ; [65536,131072) M_lo ; [131072,+32) msq[8] f32
#define MS_LO_OFF 32768   // in shorts
#define MSQ_BYTE  131072

__device__ __forceinline__ short f2bf(float v) {
  unsigned u = __builtin_bit_cast(unsigned, v);
  unsigned r = u + 0x7FFFu + ((u >> 16) & 1u);   // RNE
  return (short)(r >> 16);
}
__device__ __forceinline__ float bf2f(short h) {
  unsigned u = ((unsigned)(unsigned short)h) << 16;
  return __builtin_bit_cast(float, u);
}

// k1: build split M tables + msq, copy kernel to output tail.
__global__ __launch_bounds__(1024) void k1_build(const float* __restrict__ kern,
                                                 void* __restrict__ wsv,
                                                 float* __restrict__ out_tail) {
  const int t = threadIdx.x;
  for (int i = t; i < LC * KK; i += 1024) out_tail[i] = kern[i];
  short* MH = (short*)wsv;
  short* ML = MH + MS_LO_OFF;
  float* MSQ = (float*)((char*)wsv + MSQ_BYTE);
  const int l = t >> 7;          // t = l*128 + f
  const int f = t & 127;
  short* h = MH + t * 32;
  short* lo = ML + t * 32;
  if (f < FAC) {
    int avail[KS] = {0, 1, 2, 3, 4};
    int perm[KS];
    int rem = f;
    const int divs[4] = {24, 6, 2, 1};
    for (int i = 0; i < 4; ++i) {
      const int d = rem / divs[i];
      rem -= d * divs[i];
      perm[i] = avail[d];
      for (int j = d; j < 4 - i; ++j) avail[j] = avail[j + 1];
    }
    perm[4] = avail[0];
    const float* Kl = kern + l * KK;
    #pragma unroll
    for (int a = 0; a < KS; ++a)
      #pragma unroll
      for (int d = 0; d < KS; ++d) {
        const float v = Kl[perm[a] * KS + perm[d]];
        const short hs = f2bf(v);
        h[a * KS + d] = hs;
        lo[a * KS + d] = f2bf(v - bf2f(hs));
      }
    #pragma unroll
    for (int q = KK; q < 32; ++q) { h[q] = 0; lo[q] = 0; }
    if (f == 0) {
      float s = 0.f;
      #pragma unroll
      for (int q = 0; q < KK; ++q) s = fmaf(Kl[q], Kl[q], s);
      MSQ[l] = s;
    }
  } else {
    #pragma unroll
    for (int q = 0; q < 32; ++q) { h[q] = 0; lo[q] = 0; }
  }
}

// k2: MFMA cross-term, in-register f-max, writes UNNORMALIZED exp(-feature).
// Wave decomposition: w&1 = pixel half (64 pix), w>>1 = l half (4 l's).
__global__ __launch_bounds__(256) void k2_feat(const float* __restrict__ x,
                                               const void* __restrict__ wsv,
                                               float* __restrict__ out) {
  __shared__ short pat_hi[PIXB][PADW];
  __shared__ short pat_lo[PIXB][PADW];
  __shared__ float xsq_s[PIXB];
  const short* MH = (const short*)wsv;
  const float* MSQ = (const float*)((const char*)wsv + MSQ_BYTE);

  const int tid = threadIdx.x;
  const int w = tid >> 6;
  const int lane = tid & 63;
  const int u0 = blockIdx.x * PIXB;

  // ---- patch gather + fp32 xsq + hi/lo split, vectorized LDS writes ----
  if (tid < PIXB) {
    const int u = u0 + tid;
    const int plane = u / SS;
    const int s = u - plane * SS;
    const int ih = s / NH;
    const int iw = s - ih * NH;
    const float* xb = x + plane * (IWID * IWID) + ih * IWID + iw;
    float p[KK];
    #pragma unroll
    for (int a = 0; a < KS; ++a)
      #pragma unroll
      for (int d = 0; d < KS; ++d)
        p[a * KS + d] = xb[a * IWID + d];
    float xs = 0.f;
    #pragma unroll
    for (int q = 0; q < KK; ++q) xs = fmaf(p[q], p[q], xs);
    xsq_s[tid] = xs;
    bf16x8 ph[4], pl[4];
    #pragma unroll
    for (int c = 0; c < 4; ++c) { ph[c] = (bf16x8)(short)0; pl[c] = (bf16x8)(short)0; }
    #pragma unroll
    for (int q = 0; q < KK; ++q) {
      const short hs = f2bf(p[q]);
      ph[q >> 3][q & 7] = hs;
      pl[q >> 3][q & 7] = f2bf(p[q] - bf2f(hs));
    }
    #pragma unroll
    for (int c = 0; c < 4; ++c) {
      *(bf16x8*)&pat_hi[tid][c * 8] = ph[c];
      *(bf16x8*)&pat_lo[tid][c * 8] = pl[c];
    }
  }
  __syncthreads();

  const int pixhalf = w & 1;
  const int l0 = (w >> 1) * 4;

  // B fragments + xsq in registers, reused across this wave's 4 l's
  bf16x8 BH[4], BL[4];
  float xs4[4];
  #pragma unroll
  for (int j = 0; j < 4; ++j) {
    const int prow = (pixhalf << 6) + (j << 4) + (lane & 15);
    BH[j] = *(const bf16x8*)&pat_hi[prow][(lane >> 4) * 8];
    BL[j] = *(const bf16x8*)&pat_lo[prow][(lane >> 4) * 8];
    xs4[j] = xsq_s[prow];
  }

  const short* abase = MH + ((lane & 15) * 32) + ((lane >> 4) * 8);
  const f32x4 Z = {0.f, 0.f, 0.f, 0.f};

  #pragma unroll 1
  for (int li = 0; li < 4; ++li) {
    const int l = l0 + li;
    const short* bh = abase + l * 4096;
    bf16x8 Ah[8], Al[8];
    #pragma unroll
    for (int t = 0; t < 8; ++t) {
      Ah[t] = *(const bf16x8*)(bh + t * 512);
      Al[t] = *(const bf16x8*)(bh + t * 512 + MS_LO_OFF);
    }
    const float ml = MSQ[l];
    float mx[4];
    #pragma unroll
    for (int j = 0; j < 4; ++j) mx[j] = -INFINITY;
    #pragma unroll
    for (int t = 0; t < 8; ++t) {
      #pragma unroll
      for (int j = 0; j < 4; ++j) {
        f32x4 C = __builtin_amdgcn_mfma_f32_16x16x32_bf16(Ah[t], BH[j], Z, 0, 0, 0);
        C = __builtin_amdgcn_mfma_f32_16x16x32_bf16(Al[t], BH[j], C, 0, 0, 0);
        C = __builtin_amdgcn_mfma_f32_16x16x32_bf16(Ah[t], BL[j], C, 0, 0, 0);
        if (t < 7) {
          mx[j] = fmaxf(mx[j], fmaxf(fmaxf(C[0], C[1]), fmaxf(C[2], C[3])));
        } else if (lane < 32) {   // f-rows 112+(lane>>4)*4+r valid only for f<120
          mx[j] = fmaxf(mx[j], fmaxf(fmaxf(C[0], C[1]), fmaxf(C[2], C[3])));
        }
      }
    }
    #pragma unroll
    for (int j = 0; j < 4; ++j) {
      float m = mx[j];
      m = fmaxf(m, __shfl_xor(m, 16));
      m = fmaxf(m, __shfl_xor(m, 32));
      if (lane < 16) {
        // e = exp(-feature); feature = ml + xsq - 2*max >= 0 so e <= ~1
        const float e = expf(2.f * m - ml - xs4[j]);
        const int up = u0 + (pixhalf << 6) + (j << 4) + lane;
        const int pl = up / SS;
        const int sx = up - pl * SS;
        out[(((pl >> 1) * 16) + ((pl & 1) * 8) + l) * SS + sx] = e;
      }
    }
  }
}

// k3: per-(b,c)-row sum + normalize (single pass; data already exp'd).
__global__ __launch_bounds__(1024) void k3_norm(float* __restrict__ data) {
  const int row = blockIdx.x;   // b*16 + c
  float* __restrict__ dr = data + row * SS;
  const int tid = threadIdx.x;
  float v[4];
  float sum = 0.f;
  #pragma unroll
  for (int i = 0; i < 4; ++i) {
    const int s = tid + i * 1024;
    const float f = (s < SS) ? dr[s] : 0.f;
    v[i] = f;
    sum += f;
  }
  #pragma unroll
  for (int off = 32; off >= 1; off >>= 1) sum += __shfl_xor(sum, off);
  __shared__ float red[16];
  if ((tid & 63) == 0) red[tid >> 6] = sum;
  __syncthreads();
  float tot = 0.f;
  #pragma unroll
  for (int i = 0; i < 16; ++i) tot += red[i];
  const float inv = 1.0f / tot;
  #pragma unroll
  for (int i = 0; i < 4; ++i) {
    const int s = tid + i * 1024;
    if (s < SS) dr[s] = v[i] * inv;
  }
}

extern "C" void kernel_launch(void* const* d_in, const int* in_sizes, int n_in,
                              void* d_out, int out_size, void* d_ws, size_t ws_size,
                              hipStream_t stream) {
  const float* x = (const float*)d_in[0];
  const float* kern = (const float*)d_in[1];
  float* out = (float*)d_out;
  hipLaunchKernelGGL(k1_build, dim3(1), dim3(1024), 0, stream, kern, d_ws, out + 460800);
  hipLaunchKernelGGL(k2_feat, dim3(NBLK2), dim3(256), 0, stream, x, d_ws, out);
  hipLaunchKernelGGL(k3_norm, dim3(128), dim3(1024), 0, stream, out);
}